// Round 1
// baseline (447.100 us; speedup 1.0000x reference)
//
#include <hip/hip_runtime.h>
#include <math.h>

// Problem constants (reference: heatmaps [16,17,512,512] f32, kernel_size=3)
#define HM_W 512
#define HM_H 512
#define TILE_ROWS 4            // output rows per block
#define LDS_STRIDE 516         // 512 + 4 floats pad (stride 2064 B, 16B-aligned, +4 bank skew)
#define SIG_THRESH 0.05f

__global__ __launch_bounds__(512) void heatmap_peak_kernel(
    const float* __restrict__ in, float* __restrict__ out) {
    // LDS tile: 6 rows (4 output + 1 halo above + 1 halo below) x 512 cols
    __shared__ float s[TILE_ROWS + 2][LDS_STRIDE];

    const int tx = threadIdx.x;             // 0..127, vec4 column
    const int ty = threadIdx.y;             // 0..3,  output row within tile
    const int t  = ty * 128 + tx;           // 0..511 flat thread id
    const int y0 = blockIdx.y * TILE_ROWS;  // first output row of this tile
    const long long base = (long long)blockIdx.z * (HM_H * HM_W);

    // ---- Stage 6 rows into LDS: 6*128 = 768 float4 loads over 512 threads ----
    for (int i = t; i < (TILE_ROWS + 2) * 128; i += 512) {
        const int r  = i >> 7;        // LDS row 0..5
        const int c  = i & 127;       // vec4 col 0..127
        const int gy = y0 - 1 + r;    // global row
        float4 v;
        if (gy >= 0 && gy < HM_H) {
            v = ((const float4*)(in + base + (long long)gy * HM_W))[c];
        } else {
            v = make_float4(-INFINITY, -INFINITY, -INFINITY, -INFINITY);
        }
        *(float4*)&s[r][c * 4] = v;
    }
    __syncthreads();

    // ---- Vertical max over 3 rows (registers) ----
    const int x0 = tx * 4;
    const float4 r0 = *(const float4*)&s[ty][x0];
    const float4 r1 = *(const float4*)&s[ty + 1][x0];   // center row
    const float4 r2 = *(const float4*)&s[ty + 2][x0];

    float4 vm;
    vm.x = fmaxf(fmaxf(r0.x, r1.x), r2.x);
    vm.y = fmaxf(fmaxf(r0.y, r1.y), r2.y);
    vm.z = fmaxf(fmaxf(r0.z, r1.z), r2.z);
    vm.w = fmaxf(fmaxf(r0.w, r1.w), r2.w);

    // ---- Horizontal halo columns (vertical max of x0-1 and x0+4) ----
    const float left = (x0 == 0) ? -INFINITY
        : fmaxf(fmaxf(s[ty][x0 - 1], s[ty + 1][x0 - 1]), s[ty + 2][x0 - 1]);
    const float right = (x0 + 4 >= HM_W) ? -INFINITY
        : fmaxf(fmaxf(s[ty][x0 + 4], s[ty + 1][x0 + 4]), s[ty + 2][x0 + 4]);

    // ---- Horizontal max over 3 columns ----
    float4 hm;
    hm.x = fmaxf(left, fmaxf(vm.x, vm.y));
    hm.y = fmaxf(vm.x, fmaxf(vm.y, vm.z));
    hm.z = fmaxf(vm.y, fmaxf(vm.z, vm.w));
    hm.w = fmaxf(vm.z, fmaxf(vm.w, right));

    // ---- Peak mask + sigmoid score ----
    float4 o;
    {
        const float sc = 1.0f / (1.0f + expf(-r1.x));
        o.x = (hm.x == r1.x && sc > SIG_THRESH) ? sc : 0.0f;
    }
    {
        const float sc = 1.0f / (1.0f + expf(-r1.y));
        o.y = (hm.y == r1.y && sc > SIG_THRESH) ? sc : 0.0f;
    }
    {
        const float sc = 1.0f / (1.0f + expf(-r1.z));
        o.z = (hm.z == r1.z && sc > SIG_THRESH) ? sc : 0.0f;
    }
    {
        const float sc = 1.0f / (1.0f + expf(-r1.w));
        o.w = (hm.w == r1.w && sc > SIG_THRESH) ? sc : 0.0f;
    }

    ((float4*)(out + base + (long long)(y0 + ty) * HM_W))[tx] = o;
}

extern "C" void kernel_launch(void* const* d_in, const int* in_sizes, int n_in,
                              void* d_out, int out_size, void* d_ws, size_t ws_size,
                              hipStream_t stream) {
    const float* heatmaps = (const float*)d_in[0];
    float* out = (float*)d_out;

    const int planes = in_sizes[0] / (HM_H * HM_W);  // B*num_kps = 272

    dim3 block(128, TILE_ROWS, 1);
    dim3 grid(1, HM_H / TILE_ROWS, planes);
    heatmap_peak_kernel<<<grid, block, 0, stream>>>(heatmaps, out);
}